// Round 1
// baseline (387.104 us; speedup 1.0000x reference)
//
#include <hip/hip_runtime.h>
#include <math.h>

#define CC 512
#define HH 38
#define WW 63
#define HWSZ (HH * WW)
#define NROIS 1024
#define NP 49          // 7x7 pooled positions
#define NCG 128        // CC/4 channel groups

__device__ inline float4 lerp4(float4 a, float4 b, float w) {
    return make_float4(a.x + (b.x - a.x) * w,
                       a.y + (b.y - a.y) * w,
                       a.z + (b.z - a.z) * w,
                       a.w + (b.w - a.w) * w);
}

__device__ inline float4 max4(float4 a, float4 b) {
    return make_float4(fmaxf(a.x, b.x), fmaxf(a.y, b.y),
                       fmaxf(a.z, b.z), fmaxf(a.w, b.w));
}

// CHW (512, 38, 63) -> HWC (38*63, 512)
__global__ __launch_bounds__(256) void transpose_chw_hwc(
        const float* __restrict__ src, float* __restrict__ dst) {
    int gt = blockIdx.x * 256 + threadIdx.x;
    if (gt >= CC * HWSZ) return;
    int c  = gt & (CC - 1);   // CC = 512, pow2
    int hw = gt >> 9;
    dst[gt] = src[c * HWSZ + hw];   // coalesced write, gathered read
}

// One thread = one pooled output position p for 4 consecutive channels of one roi.
// Lane-fastest dim is cg -> corner gathers are contiguous 16B/lane (coalesced).
__global__ __launch_bounds__(256) void roi_pool_hwc(
        const float* __restrict__ img,    // HWC
        const float* __restrict__ rois,   // (N,5)
        float* __restrict__ out) {        // (N, 512, 7, 7)
    int gt = blockIdx.x * 256 + threadIdx.x;
    int cg  = gt & (NCG - 1);
    int rem = gt >> 7;
    int p = rem % NP;
    int n = rem / NP;
    if (n >= NROIS) return;

    const float* r = rois + n * 5;
    float x1 = r[1] * 0.0625f;
    float y1 = r[2] * 0.0625f;
    float x2 = r[3] * 0.0625f;
    float y2 = r[4] * 0.0625f;
    // mirror reference: normalize then rescale
    float y1n = y1 / 37.0f, y2n = y2 / 37.0f;
    float x1n = x1 / 62.0f, x2n = x2 / 62.0f;

    int ph = p / 7, pw = p % 7;

    float4 acc = make_float4(-INFINITY, -INFINITY, -INFINITY, -INFINITY);

#pragma unroll
    for (int sy = 0; sy < 2; ++sy) {
        int iy = 2 * ph + sy;
        float t = (float)iy / 13.0f;
        float in_y = (y1n + t * (y2n - y1n)) * 37.0f;
        bool vy = (in_y >= 0.0f) && (in_y <= 37.0f);
        float y0f = floorf(in_y);
        float wy = in_y - y0f;
        int yy0 = (int)fminf(fmaxf(y0f, 0.0f), 37.0f);
        int yy1 = (int)fminf(fmaxf(y0f + 1.0f, 0.0f), 37.0f);
#pragma unroll
        for (int sx = 0; sx < 2; ++sx) {
            int ix = 2 * pw + sx;
            float tx = (float)ix / 13.0f;
            float in_x = (x1n + tx * (x2n - x1n)) * 62.0f;
            bool vx = (in_x >= 0.0f) && (in_x <= 62.0f);
            float x0f = floorf(in_x);
            float wx = in_x - x0f;
            int xx0 = (int)fminf(fmaxf(x0f, 0.0f), 62.0f);
            int xx1 = (int)fminf(fmaxf(x0f + 1.0f, 0.0f), 62.0f);

            const float4* p00 = (const float4*)(img + (yy0 * WW + xx0) * CC) + cg;
            const float4* p01 = (const float4*)(img + (yy0 * WW + xx1) * CC) + cg;
            const float4* p10 = (const float4*)(img + (yy1 * WW + xx0) * CC) + cg;
            const float4* p11 = (const float4*)(img + (yy1 * WW + xx1) * CC) + cg;
            float4 g00 = *p00, g01 = *p01, g10 = *p10, g11 = *p11;

            float4 top = lerp4(g00, g01, wx);
            float4 bot = lerp4(g10, g11, wx);
            float4 val = lerp4(top, bot, wy);
            if (!(vy && vx)) val = make_float4(0.f, 0.f, 0.f, 0.f);
            acc = max4(acc, val);
        }
    }

    long obase = ((long)n * CC + cg * 4) * NP + p;
    out[obase          ] = acc.x;
    out[obase +     NP ] = acc.y;
    out[obase + 2 * NP ] = acc.z;
    out[obase + 3 * NP ] = acc.w;
}

// Fallback: direct CHW gathers (used only if ws too small for the transpose)
__global__ __launch_bounds__(256) void roi_pool_chw(
        const float* __restrict__ img,    // CHW
        const float* __restrict__ rois,
        float* __restrict__ out) {
    int gt = blockIdx.x * 256 + threadIdx.x;
    int cg  = gt & (NCG - 1);
    int rem = gt >> 7;
    int p = rem % NP;
    int n = rem / NP;
    if (n >= NROIS) return;

    const float* r = rois + n * 5;
    float x1 = r[1] * 0.0625f;
    float y1 = r[2] * 0.0625f;
    float x2 = r[3] * 0.0625f;
    float y2 = r[4] * 0.0625f;
    float y1n = y1 / 37.0f, y2n = y2 / 37.0f;
    float x1n = x1 / 62.0f, x2n = x2 / 62.0f;

    int ph = p / 7, pw = p % 7;
    float acc[4] = {-INFINITY, -INFINITY, -INFINITY, -INFINITY};

#pragma unroll
    for (int sy = 0; sy < 2; ++sy) {
        int iy = 2 * ph + sy;
        float t = (float)iy / 13.0f;
        float in_y = (y1n + t * (y2n - y1n)) * 37.0f;
        bool vy = (in_y >= 0.0f) && (in_y <= 37.0f);
        float y0f = floorf(in_y);
        float wy = in_y - y0f;
        int yy0 = (int)fminf(fmaxf(y0f, 0.0f), 37.0f);
        int yy1 = (int)fminf(fmaxf(y0f + 1.0f, 0.0f), 37.0f);
#pragma unroll
        for (int sx = 0; sx < 2; ++sx) {
            int ix = 2 * pw + sx;
            float tx = (float)ix / 13.0f;
            float in_x = (x1n + tx * (x2n - x1n)) * 62.0f;
            bool vx = (in_x >= 0.0f) && (in_x <= 62.0f);
            float x0f = floorf(in_x);
            float wx = in_x - x0f;
            int xx0 = (int)fminf(fmaxf(x0f, 0.0f), 62.0f);
            int xx1 = (int)fminf(fmaxf(x0f + 1.0f, 0.0f), 62.0f);

            int o00 = yy0 * WW + xx0, o01 = yy0 * WW + xx1;
            int o10 = yy1 * WW + xx0, o11 = yy1 * WW + xx1;
            bool valid = vy && vx;
#pragma unroll
            for (int j = 0; j < 4; ++j) {
                int c = cg * 4 + j;
                const float* s = img + c * HWSZ;
                float g00 = s[o00], g01 = s[o01], g10 = s[o10], g11 = s[o11];
                float top = g00 + (g01 - g00) * wx;
                float bot = g10 + (g11 - g10) * wx;
                float val = top + (bot - top) * wy;
                if (!valid) val = 0.0f;
                acc[j] = fmaxf(acc[j], val);
            }
        }
    }

    long obase = ((long)n * CC + cg * 4) * NP + p;
#pragma unroll
    for (int j = 0; j < 4; ++j) out[obase + (long)j * NP] = acc[j];
}

extern "C" void kernel_launch(void* const* d_in, const int* in_sizes, int n_in,
                              void* d_out, int out_size, void* d_ws, size_t ws_size,
                              hipStream_t stream) {
    const float* bottom = (const float*)d_in[0];
    const float* rois   = (const float*)d_in[1];
    float* out = (float*)d_out;

    const int total = NROIS * NP * NCG;          // 6,422,528 threads
    const int blocks = (total + 255) / 256;      // 25,088

    const size_t need = (size_t)CC * HWSZ * sizeof(float);  // ~4.9 MB
    if (ws_size >= need) {
        float* img = (float*)d_ws;
        const int te = CC * HWSZ;
        transpose_chw_hwc<<<(te + 255) / 256, 256, 0, stream>>>(bottom, img);
        roi_pool_hwc<<<blocks, 256, 0, stream>>>(img, rois, out);
    } else {
        roi_pool_chw<<<blocks, 256, 0, stream>>>(bottom, rois, out);
    }
}

// Round 2
// 249.758 us; speedup vs baseline: 1.5499x; 1.5499x over previous
//
#include <hip/hip_runtime.h>
#include <math.h>

#define CC 512
#define HH 38
#define WW 63
#define HWSZ (HH * WW)
#define NROIS 1024
#define NP 49          // 7x7 pooled positions

// ---------------- LDS-tiled transpose: CHW (512, 2394) -> HWC (2394, 512) ----
// Tile: 64 spatial x 64 channels. Both global phases coalesced; LDS padded +1.
__global__ __launch_bounds__(256) void transpose_tiled(
        const float* __restrict__ src, float* __restrict__ dst) {
    __shared__ float tile[64][65];
    int s0 = blockIdx.x * 64;
    int c0 = blockIdx.y * 64;
    int tx = threadIdx.x & 63;   // lane within wave
    int ty = threadIdx.x >> 6;   // wave id 0..3

    // read coalesced along spatial
#pragma unroll
    for (int k = 0; k < 16; ++k) {
        int c = ty * 16 + k;
        int s = s0 + tx;
        float v = (s < HWSZ) ? src[(c0 + c) * HWSZ + s] : 0.0f;
        tile[tx][c] = v;               // bank: (tx*65+c)%32 -> conflict-free
    }
    __syncthreads();
    // write coalesced along channel
#pragma unroll
    for (int k = 0; k < 16; ++k) {
        int s = ty * 16 + k;
        if (s0 + s < HWSZ)
            dst[(s0 + s) * CC + c0 + tx] = tile[s][tx];
    }
}

// ---------------- main kernel: one thread = one (n, c), all 49 outputs -------
// Lane-fastest dim is c -> every corner gather is 256B contiguous per wave.
// Each lane stores 49 consecutive floats -> full-line coverage, no write amp.
__global__ __launch_bounds__(256) void roi_pool_hwc2(
        const float* __restrict__ img,    // HWC (2394, 512)
        const float* __restrict__ rois,   // (N, 5)
        float* __restrict__ out) {        // (N, 512, 7, 7)
    int n = blockIdx.x >> 1;                            // wave-uniform
    int c = ((blockIdx.x & 1) << 8) + threadIdx.x;      // 0..511

    const float* r = rois + n * 5;
    float x1n = (r[1] * 0.0625f) / 62.0f;
    float y1n = (r[2] * 0.0625f) / 37.0f;
    float x2n = (r[3] * 0.0625f) / 62.0f;
    float y2n = (r[4] * 0.0625f) / 37.0f;
    float ydn = y2n - y1n;
    float xdn = x2n - x1n;

    const float* imgc = img + c;
    int obase = (n * CC + c) * NP;

    // precompute x-side interpolation params (unrolled -> stays in registers)
    float wxa[14];
    int   x0a[14], x1a[14];
    int   vxm = 0;
#pragma unroll
    for (int ix = 0; ix < 14; ++ix) {
        float t = (float)ix * (1.0f / 13.0f);
        float in_x = (x1n + t * xdn) * 62.0f;
        if (in_x >= 0.0f && in_x <= 62.0f) vxm |= (1 << ix);
        float x0f = floorf(in_x);
        wxa[ix] = in_x - x0f;
        int xx0 = (int)fminf(fmaxf(x0f, 0.0f), 62.0f);
        int xx1 = (int)fminf(fmaxf(x0f + 1.0f, 0.0f), 62.0f);
        x0a[ix] = xx0 * CC;
        x1a[ix] = xx1 * CC;
    }

#pragma unroll
    for (int oy = 0; oy < 7; ++oy) {
        float row[7];
#pragma unroll
        for (int ox = 0; ox < 7; ++ox) row[ox] = -INFINITY;

#pragma unroll
        for (int sy = 0; sy < 2; ++sy) {
            int iy = oy * 2 + sy;
            float t = (float)iy * (1.0f / 13.0f);
            float in_y = (y1n + t * ydn) * 37.0f;
            bool vy = (in_y >= 0.0f) && (in_y <= 37.0f);
            float y0f = floorf(in_y);
            float wy = in_y - y0f;
            int yy0 = (int)fminf(fmaxf(y0f, 0.0f), 37.0f);
            int yy1 = (int)fminf(fmaxf(y0f + 1.0f, 0.0f), 37.0f);
            int yb0 = yy0 * (WW * CC);
            int yb1 = yy1 * (WW * CC);

#pragma unroll
            for (int ox = 0; ox < 7; ++ox) {
#pragma unroll
                for (int sx = 0; sx < 2; ++sx) {
                    int ix = ox * 2 + sx;
                    float g00 = imgc[yb0 + x0a[ix]];
                    float g01 = imgc[yb0 + x1a[ix]];
                    float g10 = imgc[yb1 + x0a[ix]];
                    float g11 = imgc[yb1 + x1a[ix]];
                    float wx = wxa[ix];
                    float top = g00 + (g01 - g00) * wx;
                    float bot = g10 + (g11 - g10) * wx;
                    float val = top + (bot - top) * wy;
                    bool valid = vy && ((vxm >> ix) & 1);
                    val = valid ? val : 0.0f;
                    row[ox] = fmaxf(row[ox], val);
                }
            }
        }
#pragma unroll
        for (int ox = 0; ox < 7; ++ox) out[obase + oy * 7 + ox] = row[ox];
    }
}

// ---------------- fallback (ws too small): direct CHW gathers ----------------
__global__ __launch_bounds__(256) void roi_pool_chw(
        const float* __restrict__ img,    // CHW
        const float* __restrict__ rois,
        float* __restrict__ out) {
    int n = blockIdx.x >> 1;
    int c = ((blockIdx.x & 1) << 8) + threadIdx.x;

    const float* r = rois + n * 5;
    float x1n = (r[1] * 0.0625f) / 62.0f;
    float y1n = (r[2] * 0.0625f) / 37.0f;
    float x2n = (r[3] * 0.0625f) / 62.0f;
    float y2n = (r[4] * 0.0625f) / 37.0f;
    float ydn = y2n - y1n;
    float xdn = x2n - x1n;

    const float* imgc = img + c * HWSZ;
    int obase = (n * CC + c) * NP;

    float wxa[14];
    int   x0a[14], x1a[14];
    int   vxm = 0;
#pragma unroll
    for (int ix = 0; ix < 14; ++ix) {
        float t = (float)ix * (1.0f / 13.0f);
        float in_x = (x1n + t * xdn) * 62.0f;
        if (in_x >= 0.0f && in_x <= 62.0f) vxm |= (1 << ix);
        float x0f = floorf(in_x);
        wxa[ix] = in_x - x0f;
        x0a[ix] = (int)fminf(fmaxf(x0f, 0.0f), 62.0f);
        x1a[ix] = (int)fminf(fmaxf(x0f + 1.0f, 0.0f), 62.0f);
    }

#pragma unroll
    for (int oy = 0; oy < 7; ++oy) {
        float row[7];
#pragma unroll
        for (int ox = 0; ox < 7; ++ox) row[ox] = -INFINITY;
#pragma unroll
        for (int sy = 0; sy < 2; ++sy) {
            int iy = oy * 2 + sy;
            float t = (float)iy * (1.0f / 13.0f);
            float in_y = (y1n + t * ydn) * 37.0f;
            bool vy = (in_y >= 0.0f) && (in_y <= 37.0f);
            float y0f = floorf(in_y);
            float wy = in_y - y0f;
            int yy0 = (int)fminf(fmaxf(y0f, 0.0f), 37.0f);
            int yy1 = (int)fminf(fmaxf(y0f + 1.0f, 0.0f), 37.0f);
            int yb0 = yy0 * WW;
            int yb1 = yy1 * WW;
#pragma unroll
            for (int ox = 0; ox < 7; ++ox) {
#pragma unroll
                for (int sx = 0; sx < 2; ++sx) {
                    int ix = ox * 2 + sx;
                    float g00 = imgc[yb0 + x0a[ix]];
                    float g01 = imgc[yb0 + x1a[ix]];
                    float g10 = imgc[yb1 + x0a[ix]];
                    float g11 = imgc[yb1 + x1a[ix]];
                    float wx = wxa[ix];
                    float top = g00 + (g01 - g00) * wx;
                    float bot = g10 + (g11 - g10) * wx;
                    float val = top + (bot - top) * wy;
                    bool valid = vy && ((vxm >> ix) & 1);
                    val = valid ? val : 0.0f;
                    row[ox] = fmaxf(row[ox], val);
                }
            }
        }
#pragma unroll
        for (int ox = 0; ox < 7; ++ox) out[obase + oy * 7 + ox] = row[ox];
    }
}

extern "C" void kernel_launch(void* const* d_in, const int* in_sizes, int n_in,
                              void* d_out, int out_size, void* d_ws, size_t ws_size,
                              hipStream_t stream) {
    const float* bottom = (const float*)d_in[0];
    const float* rois   = (const float*)d_in[1];
    float* out = (float*)d_out;

    const int blocks = NROIS * 2;   // 2048; block covers 256 channels of one roi

    const size_t need = (size_t)CC * HWSZ * sizeof(float);  // ~4.9 MB
    if (ws_size >= need) {
        float* img = (float*)d_ws;
        dim3 tg((HWSZ + 63) / 64, CC / 64);   // 38 x 8
        transpose_tiled<<<tg, 256, 0, stream>>>(bottom, img);
        roi_pool_hwc2<<<blocks, 256, 0, stream>>>(img, rois, out);
    } else {
        roi_pool_chw<<<blocks, 256, 0, stream>>>(bottom, rois, out);
    }
}

// Round 3
// 231.972 us; speedup vs baseline: 1.6688x; 1.0767x over previous
//
#include <hip/hip_runtime.h>
#include <math.h>

#define CC 512
#define HH 38
#define WW 63
#define HWSZ (HH * WW)
#define NROIS 1024
#define NP 49          // 7x7 pooled positions

// ---------------- LDS-tiled transpose: CHW (512, 2394) -> HWC (2394, 512) ----
__global__ __launch_bounds__(256) void transpose_tiled(
        const float* __restrict__ src, float* __restrict__ dst) {
    __shared__ float tile[64][65];
    int s0 = blockIdx.x * 64;
    int c0 = blockIdx.y * 64;
    int tx = threadIdx.x & 63;   // lane within wave
    int ty = threadIdx.x >> 6;   // wave id 0..3

#pragma unroll
    for (int k = 0; k < 16; ++k) {
        int c = ty * 16 + k;
        int s = s0 + tx;
        float v = (s < HWSZ) ? src[(c0 + c) * HWSZ + s] : 0.0f;
        tile[tx][c] = v;
    }
    __syncthreads();
#pragma unroll
    for (int k = 0; k < 16; ++k) {
        int s = ty * 16 + k;
        if (s0 + s < HWSZ)
            dst[(s0 + s) * CC + c0 + tx] = tile[s][tx];
    }
}

// ---------------- main kernel ------------------------------------------------
// Block = 256 threads = half a roi (256 channels). One thread = one channel,
// all 49 pooled outputs. Gathers stay lane-fastest-in-c (coalesced 256B/wave).
// Outputs staged in LDS (stride 49 = odd -> conflict-free), then the whole
// contiguous 50176B half-roi region is written with dense float4 wave stores:
// full-line coverage, no read-for-ownership, no scatter cost.
__global__ __launch_bounds__(256) void roi_pool_v3(
        const float* __restrict__ img,    // HWC (2394, 512)
        const float* __restrict__ rois,   // (N, 5)
        float* __restrict__ out) {        // (N, 512, 7, 7)
    __shared__ float stage[256 * NP];     // 50176 B

    int n = blockIdx.x >> 1;                            // wave-uniform
    int h = blockIdx.x & 1;
    int t = threadIdx.x;
    int c = (h << 8) + t;

    const float* r = rois + n * 5;
    float x1n = (r[1] * 0.0625f) / 62.0f;
    float y1n = (r[2] * 0.0625f) / 37.0f;
    float x2n = (r[3] * 0.0625f) / 62.0f;
    float y2n = (r[4] * 0.0625f) / 37.0f;
    float ydn = y2n - y1n;
    float xdn = x2n - x1n;

    const float* imgc = img + c;

    // precompute x-side interpolation params (registers)
    float wxa[14];
    int   x0a[14], x1a[14];
    int   vxm = 0;
#pragma unroll
    for (int ix = 0; ix < 14; ++ix) {
        float tt = (float)ix * (1.0f / 13.0f);
        float in_x = (x1n + tt * xdn) * 62.0f;
        if (in_x >= 0.0f && in_x <= 62.0f) vxm |= (1 << ix);
        float x0f = floorf(in_x);
        wxa[ix] = in_x - x0f;
        int xx0 = (int)fminf(fmaxf(x0f, 0.0f), 62.0f);
        int xx1 = (int)fminf(fmaxf(x0f + 1.0f, 0.0f), 62.0f);
        x0a[ix] = xx0 * CC;
        x1a[ix] = xx1 * CC;
    }

#pragma unroll
    for (int oy = 0; oy < 7; ++oy) {
        float row[7];
#pragma unroll
        for (int ox = 0; ox < 7; ++ox) row[ox] = -INFINITY;

#pragma unroll
        for (int sy = 0; sy < 2; ++sy) {
            int iy = oy * 2 + sy;
            float tt = (float)iy * (1.0f / 13.0f);
            float in_y = (y1n + tt * ydn) * 37.0f;
            bool vy = (in_y >= 0.0f) && (in_y <= 37.0f);
            float y0f = floorf(in_y);
            float wy = in_y - y0f;
            int yy0 = (int)fminf(fmaxf(y0f, 0.0f), 37.0f);
            int yy1 = (int)fminf(fmaxf(y0f + 1.0f, 0.0f), 37.0f);
            int yb0 = yy0 * (WW * CC);
            int yb1 = yy1 * (WW * CC);

#pragma unroll
            for (int ox = 0; ox < 7; ++ox) {
#pragma unroll
                for (int sx = 0; sx < 2; ++sx) {
                    int ix = ox * 2 + sx;
                    float g00 = imgc[yb0 + x0a[ix]];
                    float g01 = imgc[yb0 + x1a[ix]];
                    float g10 = imgc[yb1 + x0a[ix]];
                    float g11 = imgc[yb1 + x1a[ix]];
                    float wx = wxa[ix];
                    float top = g00 + (g01 - g00) * wx;
                    float bot = g10 + (g11 - g10) * wx;
                    float val = top + (bot - top) * wy;
                    bool valid = vy && ((vxm >> ix) & 1);
                    val = valid ? val : 0.0f;
                    row[ox] = fmaxf(row[ox], val);
                }
            }
        }
#pragma unroll
        for (int ox = 0; ox < 7; ++ox)
            stage[t * NP + oy * 7 + ox] = row[ox];   // stride 49: conflict-free
    }

    __syncthreads();

    // dense coalesced store of the contiguous half-roi region (50176 B, 16B-aligned)
    const float4* s4 = (const float4*)stage;
    float4* o4 = (float4*)(out + ((n << 9) + (h << 8)) * NP);
    for (int i = t; i < (256 * NP) / 4; i += 256)    // 3136 float4
        o4[i] = s4[i];
}

// ---------------- fallback (ws too small): direct CHW gathers ----------------
__global__ __launch_bounds__(256) void roi_pool_chw(
        const float* __restrict__ img,    // CHW
        const float* __restrict__ rois,
        float* __restrict__ out) {
    __shared__ float stage[256 * NP];
    int n = blockIdx.x >> 1;
    int h = blockIdx.x & 1;
    int t = threadIdx.x;
    int c = (h << 8) + t;

    const float* r = rois + n * 5;
    float x1n = (r[1] * 0.0625f) / 62.0f;
    float y1n = (r[2] * 0.0625f) / 37.0f;
    float x2n = (r[3] * 0.0625f) / 62.0f;
    float y2n = (r[4] * 0.0625f) / 37.0f;
    float ydn = y2n - y1n;
    float xdn = x2n - x1n;

    const float* imgc = img + c * HWSZ;

    float wxa[14];
    int   x0a[14], x1a[14];
    int   vxm = 0;
#pragma unroll
    for (int ix = 0; ix < 14; ++ix) {
        float tt = (float)ix * (1.0f / 13.0f);
        float in_x = (x1n + tt * xdn) * 62.0f;
        if (in_x >= 0.0f && in_x <= 62.0f) vxm |= (1 << ix);
        float x0f = floorf(in_x);
        wxa[ix] = in_x - x0f;
        x0a[ix] = (int)fminf(fmaxf(x0f, 0.0f), 62.0f);
        x1a[ix] = (int)fminf(fmaxf(x0f + 1.0f, 0.0f), 62.0f);
    }

#pragma unroll
    for (int oy = 0; oy < 7; ++oy) {
        float row[7];
#pragma unroll
        for (int ox = 0; ox < 7; ++ox) row[ox] = -INFINITY;
#pragma unroll
        for (int sy = 0; sy < 2; ++sy) {
            int iy = oy * 2 + sy;
            float tt = (float)iy * (1.0f / 13.0f);
            float in_y = (y1n + tt * ydn) * 37.0f;
            bool vy = (in_y >= 0.0f) && (in_y <= 37.0f);
            float y0f = floorf(in_y);
            float wy = in_y - y0f;
            int yy0 = (int)fminf(fmaxf(y0f, 0.0f), 37.0f);
            int yy1 = (int)fminf(fmaxf(y0f + 1.0f, 0.0f), 37.0f);
            int yb0 = yy0 * WW;
            int yb1 = yy1 * WW;
#pragma unroll
            for (int ox = 0; ox < 7; ++ox) {
#pragma unroll
                for (int sx = 0; sx < 2; ++sx) {
                    int ix = ox * 2 + sx;
                    float g00 = imgc[yb0 + x0a[ix]];
                    float g01 = imgc[yb0 + x1a[ix]];
                    float g10 = imgc[yb1 + x0a[ix]];
                    float g11 = imgc[yb1 + x1a[ix]];
                    float wx = wxa[ix];
                    float top = g00 + (g01 - g00) * wx;
                    float bot = g10 + (g11 - g10) * wx;
                    float val = top + (bot - top) * wy;
                    bool valid = vy && ((vxm >> ix) & 1);
                    val = valid ? val : 0.0f;
                    row[ox] = fmaxf(row[ox], val);
                }
            }
        }
#pragma unroll
        for (int ox = 0; ox < 7; ++ox)
            stage[t * NP + oy * 7 + ox] = row[ox];
    }

    __syncthreads();
    const float4* s4 = (const float4*)stage;
    float4* o4 = (float4*)(out + ((n << 9) + (h << 8)) * NP);
    for (int i = t; i < (256 * NP) / 4; i += 256)
        o4[i] = s4[i];
}

extern "C" void kernel_launch(void* const* d_in, const int* in_sizes, int n_in,
                              void* d_out, int out_size, void* d_ws, size_t ws_size,
                              hipStream_t stream) {
    const float* bottom = (const float*)d_in[0];
    const float* rois   = (const float*)d_in[1];
    float* out = (float*)d_out;

    const int blocks = NROIS * 2;   // 2048

    const size_t need = (size_t)CC * HWSZ * sizeof(float);  // ~4.9 MB
    if (ws_size >= need) {
        float* img = (float*)d_ws;
        dim3 tg((HWSZ + 63) / 64, CC / 64);   // 38 x 8
        transpose_tiled<<<tg, 256, 0, stream>>>(bottom, img);
        roi_pool_v3<<<blocks, 256, 0, stream>>>(img, rois, out);
    } else {
        roi_pool_chw<<<blocks, 256, 0, stream>>>(bottom, rois, out);
    }
}